// Round 3
// baseline (113.432 us; speedup 1.0000x reference)
//
#include <hip/hip_runtime.h>

// Problem constants (from setup_inputs: B=1, S=7, C=16, H=64, W=96, D=64)
#define S_ 7
#define C_ 16
#define H_ 64
#define W_ 96
#define N_ (H_*W_)          // 6144
#define D_ 64
#define EPS_PROJ 1e-8f
#define EPS_DIV  1e-4f

// ---- fused transpose:  src (S,C,N)->(S,N,C)  and  cur (C,N)->(N,C) ----
// Writes coalesced (tid-contiguous), reads strided — strided side is the
// small L2-resident input, so this is cheap (~1 MB moved, ~5 us).
__global__ __launch_bounds__(256) void transpose_all(const float* __restrict__ src,
                                                     const float* __restrict__ cur,
                                                     float* __restrict__ src_t,
                                                     float* __restrict__ cur_t) {
    int tid = blockIdx.x * 256 + threadIdx.x;
    const int nsrc = S_ * C_ * N_;
    if (tid < nsrc) {
        int c = tid & (C_ - 1);
        int t = tid >> 4;
        int n = t % N_;
        int s = t / N_;
        src_t[tid] = src[(s * C_ + c) * N_ + n];
    } else {
        int u = tid - nsrc;
        if (u < C_ * N_) {
            int c = u & (C_ - 1);
            int n = u >> 4;
            cur_t[u] = cur[c * N_ + n];
        }
    }
}

// ---- main: one thread per output element (d, n), n fastest ----
template <bool TRANS>
__global__ __launch_bounds__(256) void cost_volume_kernel(
    const float* __restrict__ src,   // TRANS ? (S,N,C) : (S,C,N)
    const float* __restrict__ cur,   // TRANS ? (N,C)   : (C,N)
    const float* __restrict__ Ks,    // (S,4,4)
    const float* __restrict__ ext,   // (S,4,4)
    const float* __restrict__ invK,  // (4,4)
    const float* __restrict__ mind_p,
    const float* __restrict__ maxd_p,
    float* __restrict__ out)
{
    __shared__ float sP[S_][12];   // P = (K @ ext)[:3,:4] per view
    __shared__ float sdepth;       // block-uniform depth plane (256 | N_)

    int t = threadIdx.x;
    if (t < S_ * 12) {
        int s = t / 12, e = t % 12, r = e >> 2, c = e & 3;
        float acc = 0.f;
#pragma unroll
        for (int j = 0; j < 4; ++j)
            acc += Ks[s * 16 + r * 4 + j] * ext[s * 16 + j * 4 + c];
        sP[s][e] = acc;
    }
    if (t == 0) {
        int d = (blockIdx.x * 256) / N_;   // block-uniform: 256 | N_
        float mind = mind_p[0], maxd = maxd_p[0];
        sdepth = expf(logf(mind) + logf(maxd / mind) * ((float)d / (float)(D_ - 1)));
    }
    __syncthreads();

    int tid = blockIdx.x * 256 + t;      // tid = d*N_ + n  (matches output layout)
    int n = tid % N_;
    int w = n % W_, h = n / W_;

    // ray = invK[:3,:3] @ (w+0.5, h+0.5, 1)
    float pxc = w + 0.5f, pyc = h + 0.5f;
    float rx = invK[0] * pxc + invK[1] * pyc + invK[2];
    float ry = invK[4] * pxc + invK[5] * pyc + invK[6];
    float rz = invK[8] * pxc + invK[9] * pyc + invK[10];

    float depth = sdepth;
    float wx = rx * depth, wy = ry * depth, wz = rz * depth;

    // current-frame feature vector (reused across all 7 views x 4 corners)
    float cf[16];
    if (TRANS) {
#pragma unroll
        for (int c = 0; c < 16; c += 4) {
            float4 v = *(const float4*)(cur + n * C_ + c);
            cf[c] = v.x; cf[c + 1] = v.y; cf[c + 2] = v.z; cf[c + 3] = v.w;
        }
    } else {
#pragma unroll
        for (int c = 0; c < 16; ++c) cf[c] = cur[c * N_ + n];
    }

    float cost = 0.f, mcnt = 0.f;
#pragma unroll
    for (int s = 0; s < S_; ++s) {
        const float* p = sP[s];
        float cx = p[0] * wx + p[1] * wy + p[2]  * wz + p[3];
        float cy = p[4] * wx + p[5] * wy + p[6]  * wz + p[7];
        float cz = p[8] * wx + p[9] * wy + p[10] * wz + p[11];

        float iz = 1.f / (cz + EPS_PROJ);      // exact f32 div (matches reference)
        float x = cx * iz - 0.5f;
        float y = cy * iz - 0.5f;

        float x0f = floorf(x), y0f = floorf(y);
        float fx1 = x - x0f, fy1 = y - y0f;
        float fx0 = 1.f - fx1, fy0 = 1.f - fy1;

        const float* sf = src + (size_t)s * (C_ * N_);  // same total stride both layouts
        float dsum = 0.f;

        float ys[2]  = {y0f, y0f + 1.f};
        float wys[2] = {fy0, fy1};
        float xs[2]  = {x0f, x0f + 1.f};
        float wxs[2] = {fx0, fx1};
#pragma unroll
        for (int ci = 0; ci < 2; ++ci) {       // y corner
            float yf = ys[ci];
            bool vy = (yf >= 0.f) && (yf <= (float)(H_ - 1));
            if (!vy) continue;
            int rowbase = (int)yf * W_;
#pragma unroll
            for (int cj = 0; cj < 2; ++cj) {   // x corner
                float xf = xs[cj];
                bool vx = (xf >= 0.f) && (xf <= (float)(W_ - 1));
                if (vx) {
                    int idx = rowbase + (int)xf;       // safe: guarded in-range
                    float dotp = 0.f;
                    if (TRANS) {
                        const float4* fp = (const float4*)(sf + idx * C_);
#pragma unroll
                        for (int q = 0; q < 4; ++q) {
                            float4 fv = fp[q];
                            dotp += fv.x * cf[4 * q]     + fv.y * cf[4 * q + 1]
                                  + fv.z * cf[4 * q + 2] + fv.w * cf[4 * q + 3];
                        }
                    } else {
#pragma unroll
                        for (int c = 0; c < 16; ++c) dotp += sf[c * N_ + idx] * cf[c];
                    }
                    dsum += wxs[cj] * wys[ci] * dotp;
                }
            }
        }
        float m = (cz > 0.f) ? 1.f : 0.f;      // mask on pre-eps z, matches reference
        cost += m * dsum;
        mcnt += m;
    }
    out[tid] = cost / (mcnt + EPS_DIV);
}

extern "C" void kernel_launch(void* const* d_in, const int* in_sizes, int n_in,
                              void* d_out, int out_size, void* d_ws, size_t ws_size,
                              hipStream_t stream) {
    const float* cur  = (const float*)d_in[0];  // (1,C,H,W)
    const float* src  = (const float*)d_in[1];  // (1,S,C,H,W)
    const float* ext  = (const float*)d_in[2];  // (1,S,4,4)
    // d_in[3] = src_poses (unused by reference)
    const float* Ks   = (const float*)d_in[4];  // (1,S,4,4)
    const float* invK = (const float*)d_in[5];  // (1,4,4)
    const float* mind = (const float*)d_in[6];
    const float* maxd = (const float*)d_in[7];
    float* out = (float*)d_out;                 // (1,D,H,W)

    const size_t need = (size_t)(S_ * N_ * C_ + N_ * C_) * sizeof(float); // ~3.15 MB
    if (ws_size >= need) {
        float* src_t = (float*)d_ws;
        float* cur_t = src_t + (size_t)S_ * N_ * C_;
        const int tot = (S_ + 1) * C_ * N_;
        transpose_all<<<(tot + 255) / 256, 256, 0, stream>>>(src, cur, src_t, cur_t);
        cost_volume_kernel<true><<<D_ * N_ / 256, 256, 0, stream>>>(
            src_t, cur_t, Ks, ext, invK, mind, maxd, out);
    } else {
        cost_volume_kernel<false><<<D_ * N_ / 256, 256, 0, stream>>>(
            src, cur, Ks, ext, invK, mind, maxd, out);
    }
}

// Round 4
// 105.047 us; speedup vs baseline: 1.0798x; 1.0798x over previous
//
#include <hip/hip_runtime.h>

// Problem constants (from setup_inputs: B=1, S=7, C=16, H=64, W=96, D=64)
#define S_ 7
#define C_ 16
#define H_ 64
#define W_ 96
#define N_ (H_*W_)          // 6144
#define D_ 64
#define EPS_PROJ 1e-8f
#define EPS_DIV  1e-4f

// ---- fused transpose:  src (S,C,N)->(S,N,C)  and  cur (C,N)->(N,C) ----
__global__ __launch_bounds__(256) void transpose_all(const float* __restrict__ src,
                                                     const float* __restrict__ cur,
                                                     float* __restrict__ src_t,
                                                     float* __restrict__ cur_t) {
    int tid = blockIdx.x * 256 + threadIdx.x;
    const int nsrc = S_ * C_ * N_;
    if (tid < nsrc) {
        int c = tid & (C_ - 1);
        int t = tid >> 4;
        int n = t % N_;
        int s = t / N_;
        src_t[tid] = src[(s * C_ + c) * N_ + n];
    } else {
        int u = tid - nsrc;
        if (u < C_ * N_) {
            int c = u & (C_ - 1);
            int n = u >> 4;
            cur_t[u] = cur[c * N_ + n];
        }
    }
}

// ---- quad-cooperative main kernel ----
// One OUTPUT per lane, but gathers are quad-cooperative: lane l4 of each quad
// loads the 16B quarter l4 of a corner's 64B feature line, so every line is
// fully consumed by a single load instruction (4x fewer L1 transactions than
// per-lane float4x4 loads). x/y are broadcast within the quad via shfl;
// quarter-dots are reduced with two width-4 shfl_xors.
__global__ __launch_bounds__(256, 4) void cost_volume_quad(
    const float* __restrict__ src_t,  // (S, N, C) channel-contiguous
    const float* __restrict__ cur_t,  // (N, C)
    const float* __restrict__ Ks,     // (S,4,4)
    const float* __restrict__ ext,    // (S,4,4)
    const float* __restrict__ invK,   // (4,4)
    const float* __restrict__ mind_p,
    const float* __restrict__ maxd_p,
    float* __restrict__ out)
{
    __shared__ float sP[S_][12];   // P = (K @ ext)[:3,:4] per view
    __shared__ float sdepth;       // block-uniform depth plane (256 | N_)

    int t = threadIdx.x;
    if (t < S_ * 12) {
        int s = t / 12, e = t % 12, r = e >> 2, c = e & 3;
        float acc = 0.f;
#pragma unroll
        for (int j = 0; j < 4; ++j)
            acc += Ks[s * 16 + r * 4 + j] * ext[s * 16 + j * 4 + c];
        sP[s][e] = acc;
    }
    if (t == 0) {
        int d = (blockIdx.x * 256) / N_;   // block-uniform: 256 | N_
        float mind = mind_p[0], maxd = maxd_p[0];
        sdepth = expf(logf(mind) + logf(maxd / mind) * ((float)d / (float)(D_ - 1)));
    }
    __syncthreads();

    int tid = blockIdx.x * 256 + t;      // tid = d*N_ + n
    int n  = tid % N_;
    int l4 = t & 3;
    int n0 = n - l4;                     // quad's base pixel (owns n0..n0+3)
    int w = n % W_, h = n / W_;

    // ray = invK[:3,:3] @ (w+0.5, h+0.5, 1)
    float pxc = w + 0.5f, pyc = h + 0.5f;
    float rx = invK[0] * pxc + invK[1] * pyc + invK[2];
    float ry = invK[4] * pxc + invK[5] * pyc + invK[6];
    float rz = invK[8] * pxc + invK[9] * pyc + invK[10];

    float depth = sdepth;
    float wx = rx * depth, wy = ry * depth, wz = rz * depth;

    // cur-feature quarter l4 for each of the quad's 4 outputs (full-line use)
    float4 cfq[4];
#pragma unroll
    for (int j = 0; j < 4; ++j)
        cfq[j] = *(const float4*)(cur_t + (n0 + j) * C_ + l4 * 4);

    float pc[4] = {0.f, 0.f, 0.f, 0.f};  // partial (quarter) dot per quad output
    float mcnt = 0.f;                    // own-output mask count

#pragma unroll
    for (int s = 0; s < S_; ++s) {
        const float* p = sP[s];
        float cx = p[0] * wx + p[1] * wy + p[2]  * wz + p[3];
        float cy = p[4] * wx + p[5] * wy + p[6]  * wz + p[7];
        float cz = p[8] * wx + p[9] * wy + p[10] * wz + p[11];

        float iz = 1.f / (cz + EPS_PROJ);
        float x = cx * iz - 0.5f;
        float y = cy * iz - 0.5f;

        mcnt += (cz > 0.f) ? 1.f : 0.f;
        if (cz <= 0.f) { x = -1e8f; y = -1e8f; }   // forces all corner weights to 0

        const float* sf = src_t + s * (C_ * N_) + l4 * 4;  // quarter-offset base

#pragma unroll
        for (int j = 0; j < 4; ++j) {
            float xj = __shfl(x, j, 4);
            float yj = __shfl(y, j, 4);

            float x0f = floorf(xj), y0f = floorf(yj);
            float fx1 = xj - x0f,  fy1 = yj - y0f;
            float fx0 = 1.f - fx1, fy0 = 1.f - fy1;
            float x1f = x0f + 1.f, y1f = y0f + 1.f;

            // validity folded into weights (zeros-padding semantics)
            float vx0 = (x0f >= 0.f && x0f <= (float)(W_ - 1)) ? fx0 : 0.f;
            float vx1 = (x1f >= 0.f && x1f <= (float)(W_ - 1)) ? fx1 : 0.f;
            float vy0 = (y0f >= 0.f && y0f <= (float)(H_ - 1)) ? fy0 : 0.f;
            float vy1 = (y1f >= 0.f && y1f <= (float)(H_ - 1)) ? fy1 : 0.f;

            // clamped integer coords (always a safe address; weight kills OOB)
            int ix0 = (int)fminf(fmaxf(x0f, 0.f), (float)(W_ - 1));
            int ix1 = (int)fminf(fmaxf(x1f, 0.f), (float)(W_ - 1));
            int iy0 = (int)fminf(fmaxf(y0f, 0.f), (float)(H_ - 1));
            int iy1 = (int)fminf(fmaxf(y1f, 0.f), (float)(H_ - 1));

            int r0 = iy0 * W_, r1 = iy1 * W_;
            float4 g00 = *(const float4*)(sf + (r0 + ix0) * C_);
            float4 g01 = *(const float4*)(sf + (r0 + ix1) * C_);
            float4 g10 = *(const float4*)(sf + (r1 + ix0) * C_);
            float4 g11 = *(const float4*)(sf + (r1 + ix1) * C_);

            float4 cq = cfq[j];
            float d00 = g00.x * cq.x + g00.y * cq.y + g00.z * cq.z + g00.w * cq.w;
            float d01 = g01.x * cq.x + g01.y * cq.y + g01.z * cq.z + g01.w * cq.w;
            float d10 = g10.x * cq.x + g10.y * cq.y + g10.z * cq.z + g10.w * cq.w;
            float d11 = g11.x * cq.x + g11.y * cq.y + g11.z * cq.z + g11.w * cq.w;

            pc[j] += (vx0 * vy0) * d00 + (vx1 * vy0) * d01
                   + (vx0 * vy1) * d10 + (vx1 * vy1) * d11;
        }
    }

    // quad reduction: every lane ends with the full sum for each quad output
#pragma unroll
    for (int j = 0; j < 4; ++j) {
        pc[j] += __shfl_xor(pc[j], 1, 4);
        pc[j] += __shfl_xor(pc[j], 2, 4);
    }
    // lane l4 owns output n0+l4 — static-index select (no scratch)
    float total = (l4 == 0) ? pc[0] : (l4 == 1) ? pc[1] : (l4 == 2) ? pc[2] : pc[3];
    out[tid] = total / (mcnt + EPS_DIV);
}

// ---- fallback scalar kernel (no workspace): src (S,C,N), cur (C,N) ----
__global__ __launch_bounds__(256) void cost_volume_scalar(
    const float* __restrict__ src, const float* __restrict__ cur,
    const float* __restrict__ Ks, const float* __restrict__ ext,
    const float* __restrict__ invK,
    const float* __restrict__ mind_p, const float* __restrict__ maxd_p,
    float* __restrict__ out)
{
    __shared__ float sP[S_][12];
    __shared__ float sdepth;
    int t = threadIdx.x;
    if (t < S_ * 12) {
        int s = t / 12, e = t % 12, r = e >> 2, c = e & 3;
        float acc = 0.f;
#pragma unroll
        for (int j = 0; j < 4; ++j)
            acc += Ks[s * 16 + r * 4 + j] * ext[s * 16 + j * 4 + c];
        sP[s][e] = acc;
    }
    if (t == 0) {
        int d = (blockIdx.x * 256) / N_;
        float mind = mind_p[0], maxd = maxd_p[0];
        sdepth = expf(logf(mind) + logf(maxd / mind) * ((float)d / (float)(D_ - 1)));
    }
    __syncthreads();

    int tid = blockIdx.x * 256 + t;
    int n = tid % N_;
    int w = n % W_, h = n / W_;
    float pxc = w + 0.5f, pyc = h + 0.5f;
    float rx = invK[0] * pxc + invK[1] * pyc + invK[2];
    float ry = invK[4] * pxc + invK[5] * pyc + invK[6];
    float rz = invK[8] * pxc + invK[9] * pyc + invK[10];
    float depth = sdepth;
    float wx = rx * depth, wy = ry * depth, wz = rz * depth;

    float cf[16];
#pragma unroll
    for (int c = 0; c < 16; ++c) cf[c] = cur[c * N_ + n];

    float cost = 0.f, mcnt = 0.f;
#pragma unroll
    for (int s = 0; s < S_; ++s) {
        const float* p = sP[s];
        float cx = p[0] * wx + p[1] * wy + p[2]  * wz + p[3];
        float cy = p[4] * wx + p[5] * wy + p[6]  * wz + p[7];
        float cz = p[8] * wx + p[9] * wy + p[10] * wz + p[11];
        float iz = 1.f / (cz + EPS_PROJ);
        float x = cx * iz - 0.5f;
        float y = cy * iz - 0.5f;
        float x0f = floorf(x), y0f = floorf(y);
        float fx1 = x - x0f, fy1 = y - y0f;
        float fx0 = 1.f - fx1, fy0 = 1.f - fy1;
        const float* sf = src + (size_t)s * (C_ * N_);
        float dsum = 0.f;
        float ys[2] = {y0f, y0f + 1.f}, wys[2] = {fy0, fy1};
        float xs[2] = {x0f, x0f + 1.f}, wxs[2] = {fx0, fx1};
#pragma unroll
        for (int ci = 0; ci < 2; ++ci) {
            float yf = ys[ci];
            if (!(yf >= 0.f && yf <= (float)(H_ - 1))) continue;
            int rowbase = (int)yf * W_;
#pragma unroll
            for (int cj = 0; cj < 2; ++cj) {
                float xf = xs[cj];
                if (xf >= 0.f && xf <= (float)(W_ - 1)) {
                    int idx = rowbase + (int)xf;
                    float dotp = 0.f;
#pragma unroll
                    for (int c = 0; c < 16; ++c) dotp += sf[c * N_ + idx] * cf[c];
                    dsum += wxs[cj] * wys[ci] * dotp;
                }
            }
        }
        float m = (cz > 0.f) ? 1.f : 0.f;
        cost += m * dsum;
        mcnt += m;
    }
    out[tid] = cost / (mcnt + EPS_DIV);
}

extern "C" void kernel_launch(void* const* d_in, const int* in_sizes, int n_in,
                              void* d_out, int out_size, void* d_ws, size_t ws_size,
                              hipStream_t stream) {
    const float* cur  = (const float*)d_in[0];  // (1,C,H,W)
    const float* src  = (const float*)d_in[1];  // (1,S,C,H,W)
    const float* ext  = (const float*)d_in[2];  // (1,S,4,4)
    // d_in[3] = src_poses (unused by reference)
    const float* Ks   = (const float*)d_in[4];  // (1,S,4,4)
    const float* invK = (const float*)d_in[5];  // (1,4,4)
    const float* mind = (const float*)d_in[6];
    const float* maxd = (const float*)d_in[7];
    float* out = (float*)d_out;                 // (1,D,H,W)

    const size_t need = (size_t)(S_ * N_ * C_ + N_ * C_) * sizeof(float); // ~3.15 MB
    if (ws_size >= need) {
        float* src_t = (float*)d_ws;
        float* cur_t = src_t + (size_t)S_ * N_ * C_;
        const int tot = (S_ + 1) * C_ * N_;
        transpose_all<<<(tot + 255) / 256, 256, 0, stream>>>(src, cur, src_t, cur_t);
        cost_volume_quad<<<D_ * N_ / 256, 256, 0, stream>>>(
            src_t, cur_t, Ks, ext, invK, mind, maxd, out);
    } else {
        cost_volume_scalar<<<D_ * N_ / 256, 256, 0, stream>>>(
            src, cur, Ks, ext, invK, mind, maxd, out);
    }
}

// Round 5
// 100.444 us; speedup vs baseline: 1.1293x; 1.0458x over previous
//
#include <hip/hip_runtime.h>

// Problem constants (from setup_inputs: B=1, S=7, C=16, H=64, W=96, D=64)
#define S_ 7
#define C_ 16
#define H_ 64
#define W_ 96
#define N_ (H_*W_)          // 6144
#define D_ 64
#define EPS_PROJ 1e-8f
#define EPS_DIV  1e-4f

// ---- fused transpose:  src (S,C,N)->(S,N,C)  and  cur (C,N)->(N,C) ----
__global__ __launch_bounds__(256) void transpose_all(const float* __restrict__ src,
                                                     const float* __restrict__ cur,
                                                     float* __restrict__ src_t,
                                                     float* __restrict__ cur_t) {
    int tid = blockIdx.x * 256 + threadIdx.x;
    const int nsrc = S_ * C_ * N_;
    if (tid < nsrc) {
        int c = tid & (C_ - 1);
        int t = tid >> 4;
        int n = t % N_;
        int s = t / N_;
        src_t[tid] = src[(s * C_ + c) * N_ + n];
    } else {
        int u = tid - nsrc;
        if (u < C_ * N_) {
            int c = u & (C_ - 1);
            int n = u >> 4;
            cur_t[u] = cur[c * N_ + n];
        }
    }
}

// ---- quad-cooperative main kernel, ILP-batched ----
// One OUTPUT per lane; gathers are quad-cooperative (lane l4 loads 16B quarter
// l4 of each corner's 64B feature line). Per view, ALL 16 corner loads are
// issued as one batch (phase A: addresses+weights, B: loads, C: dots) so the
// memory latency of the gather is covered by ILP, not just TLP.
// __launch_bounds__(256,3): VGPR cap ~170 so the 16 float4 destinations stay
// in registers (r3 compiled to 32 VGPR and serialized the gather).
__global__ __launch_bounds__(256, 3) void cost_volume_quad(
    const float* __restrict__ src_t,  // (S, N, C) channel-contiguous
    const float* __restrict__ cur_t,  // (N, C)
    const float* __restrict__ Ks,     // (S,4,4)
    const float* __restrict__ ext,    // (S,4,4)
    const float* __restrict__ invK,   // (4,4)
    const float* __restrict__ mind_p,
    const float* __restrict__ maxd_p,
    float* __restrict__ out)
{
    __shared__ float sP[S_][12];   // P = (K @ ext)[:3,:4] per view
    __shared__ float sdepth;       // block-uniform depth plane (256 | N_)

    int t = threadIdx.x;
    if (t < S_ * 12) {
        int s = t / 12, e = t % 12, r = e >> 2, c = e & 3;
        float acc = 0.f;
#pragma unroll
        for (int j = 0; j < 4; ++j)
            acc += Ks[s * 16 + r * 4 + j] * ext[s * 16 + j * 4 + c];
        sP[s][e] = acc;
    }
    if (t == 0) {
        int d = (blockIdx.x * 256) / N_;   // block-uniform: 256 | N_
        float mind = mind_p[0], maxd = maxd_p[0];
        sdepth = expf(logf(mind) + logf(maxd / mind) * ((float)d / (float)(D_ - 1)));
    }
    __syncthreads();

    int tid = blockIdx.x * 256 + t;      // tid = d*N_ + n
    int n  = tid % N_;
    int l4 = t & 3;
    int n0 = n - l4;                     // quad's base pixel (owns n0..n0+3)
    int w = n % W_, h = n / W_;

    // ray = invK[:3,:3] @ (w+0.5, h+0.5, 1)
    float pxc = w + 0.5f, pyc = h + 0.5f;
    float rx = invK[0] * pxc + invK[1] * pyc + invK[2];
    float ry = invK[4] * pxc + invK[5] * pyc + invK[6];
    float rz = invK[8] * pxc + invK[9] * pyc + invK[10];

    float depth = sdepth;
    float wx = rx * depth, wy = ry * depth, wz = rz * depth;

    // cur-feature quarter l4 for each of the quad's 4 outputs
    float4 cfq[4];
#pragma unroll
    for (int j = 0; j < 4; ++j)
        cfq[j] = *(const float4*)(cur_t + (n0 + j) * C_ + l4 * 4);

    float pc[4] = {0.f, 0.f, 0.f, 0.f};  // partial (quarter) dot per quad output
    float mcnt = 0.f;                    // own-output mask count

#pragma unroll
    for (int s = 0; s < S_; ++s) {
        const float* p = sP[s];
        float cx = p[0] * wx + p[1] * wy + p[2]  * wz + p[3];
        float cy = p[4] * wx + p[5] * wy + p[6]  * wz + p[7];
        float cz = p[8] * wx + p[9] * wy + p[10] * wz + p[11];

        float iz = 1.f / (cz + EPS_PROJ);
        float x = cx * iz - 0.5f;
        float y = cy * iz - 0.5f;

        mcnt += (cz > 0.f) ? 1.f : 0.f;
        if (cz <= 0.f) { x = -1e8f; y = -1e8f; }   // all corner weights -> 0

        const float* sf = src_t + s * (C_ * N_) + l4 * 4;  // quarter-offset base

        // broadcast quad outputs' coords
        float xj[4], yj[4];
#pragma unroll
        for (int j = 0; j < 4; ++j) {
            xj[j] = __shfl(x, j, 4);
            yj[j] = __shfl(y, j, 4);
        }

        // --- phase A: all 16 corner offsets + weights ---
        int   off[16];
        float wgt[16];
#pragma unroll
        for (int j = 0; j < 4; ++j) {
            float x0f = floorf(xj[j]), y0f = floorf(yj[j]);
            float fx1 = xj[j] - x0f,  fy1 = yj[j] - y0f;
            float fx0 = 1.f - fx1, fy0 = 1.f - fy1;
            float x1f = x0f + 1.f, y1f = y0f + 1.f;

            float vx0 = (x0f >= 0.f && x0f <= (float)(W_ - 1)) ? fx0 : 0.f;
            float vx1 = (x1f >= 0.f && x1f <= (float)(W_ - 1)) ? fx1 : 0.f;
            float vy0 = (y0f >= 0.f && y0f <= (float)(H_ - 1)) ? fy0 : 0.f;
            float vy1 = (y1f >= 0.f && y1f <= (float)(H_ - 1)) ? fy1 : 0.f;

            int ix0 = (int)fminf(fmaxf(x0f, 0.f), (float)(W_ - 1));
            int ix1 = (int)fminf(fmaxf(x1f, 0.f), (float)(W_ - 1));
            int iy0 = (int)fminf(fmaxf(y0f, 0.f), (float)(H_ - 1));
            int iy1 = (int)fminf(fmaxf(y1f, 0.f), (float)(H_ - 1));

            int r0 = iy0 * W_, r1 = iy1 * W_;
            off[j * 4 + 0] = (r0 + ix0) * C_;
            off[j * 4 + 1] = (r0 + ix1) * C_;
            off[j * 4 + 2] = (r1 + ix0) * C_;
            off[j * 4 + 3] = (r1 + ix1) * C_;
            wgt[j * 4 + 0] = vx0 * vy0;
            wgt[j * 4 + 1] = vx1 * vy0;
            wgt[j * 4 + 2] = vx0 * vy1;
            wgt[j * 4 + 3] = vx1 * vy1;
        }

        // --- phase B: issue all 16 gathers as a batch ---
        float4 g[16];
#pragma unroll
        for (int k = 0; k < 16; ++k)
            g[k] = *(const float4*)(sf + off[k]);

        // --- phase C: dots + weighted accumulate ---
#pragma unroll
        for (int j = 0; j < 4; ++j) {
            float4 cq = cfq[j];
#pragma unroll
            for (int c = 0; c < 4; ++c) {
                float4 gv = g[j * 4 + c];
                float d = gv.x * cq.x + gv.y * cq.y + gv.z * cq.z + gv.w * cq.w;
                pc[j] += wgt[j * 4 + c] * d;
            }
        }
    }

    // quad reduction: full sum for each quad output
#pragma unroll
    for (int j = 0; j < 4; ++j) {
        pc[j] += __shfl_xor(pc[j], 1, 4);
        pc[j] += __shfl_xor(pc[j], 2, 4);
    }
    float total = (l4 == 0) ? pc[0] : (l4 == 1) ? pc[1] : (l4 == 2) ? pc[2] : pc[3];
    out[tid] = total / (mcnt + EPS_DIV);
}

// ---- fallback scalar kernel (no workspace): src (S,C,N), cur (C,N) ----
__global__ __launch_bounds__(256) void cost_volume_scalar(
    const float* __restrict__ src, const float* __restrict__ cur,
    const float* __restrict__ Ks, const float* __restrict__ ext,
    const float* __restrict__ invK,
    const float* __restrict__ mind_p, const float* __restrict__ maxd_p,
    float* __restrict__ out)
{
    __shared__ float sP[S_][12];
    __shared__ float sdepth;
    int t = threadIdx.x;
    if (t < S_ * 12) {
        int s = t / 12, e = t % 12, r = e >> 2, c = e & 3;
        float acc = 0.f;
#pragma unroll
        for (int j = 0; j < 4; ++j)
            acc += Ks[s * 16 + r * 4 + j] * ext[s * 16 + j * 4 + c];
        sP[s][e] = acc;
    }
    if (t == 0) {
        int d = (blockIdx.x * 256) / N_;
        float mind = mind_p[0], maxd = maxd_p[0];
        sdepth = expf(logf(mind) + logf(maxd / mind) * ((float)d / (float)(D_ - 1)));
    }
    __syncthreads();

    int tid = blockIdx.x * 256 + t;
    int n = tid % N_;
    int w = n % W_, h = n / W_;
    float pxc = w + 0.5f, pyc = h + 0.5f;
    float rx = invK[0] * pxc + invK[1] * pyc + invK[2];
    float ry = invK[4] * pxc + invK[5] * pyc + invK[6];
    float rz = invK[8] * pxc + invK[9] * pyc + invK[10];
    float depth = sdepth;
    float wx = rx * depth, wy = ry * depth, wz = rz * depth;

    float cf[16];
#pragma unroll
    for (int c = 0; c < 16; ++c) cf[c] = cur[c * N_ + n];

    float cost = 0.f, mcnt = 0.f;
#pragma unroll
    for (int s = 0; s < S_; ++s) {
        const float* p = sP[s];
        float cx = p[0] * wx + p[1] * wy + p[2]  * wz + p[3];
        float cy = p[4] * wx + p[5] * wy + p[6]  * wz + p[7];
        float cz = p[8] * wx + p[9] * wy + p[10] * wz + p[11];
        float iz = 1.f / (cz + EPS_PROJ);
        float x = cx * iz - 0.5f;
        float y = cy * iz - 0.5f;
        float x0f = floorf(x), y0f = floorf(y);
        float fx1 = x - x0f, fy1 = y - y0f;
        float fx0 = 1.f - fx1, fy0 = 1.f - fy1;
        const float* sf = src + (size_t)s * (C_ * N_);
        float dsum = 0.f;
        float ys[2] = {y0f, y0f + 1.f}, wys[2] = {fy0, fy1};
        float xs[2] = {x0f, x0f + 1.f}, wxs[2] = {fx0, fx1};
#pragma unroll
        for (int ci = 0; ci < 2; ++ci) {
            float yf = ys[ci];
            if (!(yf >= 0.f && yf <= (float)(H_ - 1))) continue;
            int rowbase = (int)yf * W_;
#pragma unroll
            for (int cj = 0; cj < 2; ++cj) {
                float xf = xs[cj];
                if (xf >= 0.f && xf <= (float)(W_ - 1)) {
                    int idx = rowbase + (int)xf;
                    float dotp = 0.f;
#pragma unroll
                    for (int c = 0; c < 16; ++c) dotp += sf[c * N_ + idx] * cf[c];
                    dsum += wxs[cj] * wys[ci] * dotp;
                }
            }
        }
        float m = (cz > 0.f) ? 1.f : 0.f;
        cost += m * dsum;
        mcnt += m;
    }
    out[tid] = cost / (mcnt + EPS_DIV);
}

extern "C" void kernel_launch(void* const* d_in, const int* in_sizes, int n_in,
                              void* d_out, int out_size, void* d_ws, size_t ws_size,
                              hipStream_t stream) {
    const float* cur  = (const float*)d_in[0];  // (1,C,H,W)
    const float* src  = (const float*)d_in[1];  // (1,S,C,H,W)
    const float* ext  = (const float*)d_in[2];  // (1,S,4,4)
    // d_in[3] = src_poses (unused by reference)
    const float* Ks   = (const float*)d_in[4];  // (1,S,4,4)
    const float* invK = (const float*)d_in[5];  // (1,4,4)
    const float* mind = (const float*)d_in[6];
    const float* maxd = (const float*)d_in[7];
    float* out = (float*)d_out;                 // (1,D,H,W)

    const size_t need = (size_t)(S_ * N_ * C_ + N_ * C_) * sizeof(float); // ~3.15 MB
    if (ws_size >= need) {
        float* src_t = (float*)d_ws;
        float* cur_t = src_t + (size_t)S_ * N_ * C_;
        const int tot = (S_ + 1) * C_ * N_;
        transpose_all<<<(tot + 255) / 256, 256, 0, stream>>>(src, cur, src_t, cur_t);
        cost_volume_quad<<<D_ * N_ / 256, 256, 0, stream>>>(
            src_t, cur_t, Ks, ext, invK, mind, maxd, out);
    } else {
        cost_volume_scalar<<<D_ * N_ / 256, 256, 0, stream>>>(
            src, cur, Ks, ext, invK, mind, maxd, out);
    }
}

// Round 6
// 98.829 us; speedup vs baseline: 1.1478x; 1.0163x over previous
//
#include <hip/hip_runtime.h>

// Problem constants (from setup_inputs: B=1, S=7, C=16, H=64, W=96, D=64)
#define S_ 7
#define C_ 16
#define H_ 64
#define W_ 96
#define N_ (H_*W_)          // 6144
#define D_ 64
#define EPS_PROJ 1e-8f
#define EPS_DIV  1e-4f

// ---- fused transpose:  src (S,C,N)->(S,N,C)  and  cur (C,N)->(N,C) ----
__global__ __launch_bounds__(256) void transpose_all(const float* __restrict__ src,
                                                     const float* __restrict__ cur,
                                                     float* __restrict__ src_t,
                                                     float* __restrict__ cur_t) {
    int tid = blockIdx.x * 256 + threadIdx.x;
    const int nsrc = S_ * C_ * N_;
    if (tid < nsrc) {
        int c = tid & (C_ - 1);
        int t = tid >> 4;
        int n = t % N_;
        int s = t / N_;
        src_t[tid] = src[(s * C_ + c) * N_ + n];
    } else {
        int u = tid - nsrc;
        if (u < C_ * N_) {
            int c = u & (C_ - 1);
            int n = u >> 4;
            cur_t[u] = cur[c * N_ + n];
        }
    }
}

// ---- quad-cooperative, depth-along-wave main kernel ----
// Block = ONE pixel-quad (4 consecutive n) x all 64 depth planes.
// lane: l4 = tid&3 (feature quarter / output-within-quad), d = tid>>2.
// A wave's 16 quads share the same 4 pixels at 16 CONSECUTIVE depths, so the
// 16 lines touched by each gather instruction lie on a short epipolar segment
// and mostly merge in the TA (one 64B line = one pixel's features). This cuts
// unique-line transactions ~2x vs the depth-uniform mapping (r5).
// Per-view structure (A: addrs+weights, B: batched loads, C: dots) unchanged.
__global__ __launch_bounds__(256, 3) void cost_volume_quad_d(
    const float* __restrict__ src_t,  // (S, N, C) channel-contiguous
    const float* __restrict__ cur_t,  // (N, C)
    const float* __restrict__ Ks,     // (S,4,4)
    const float* __restrict__ ext,    // (S,4,4)
    const float* __restrict__ invK,   // (4,4)
    const float* __restrict__ mind_p,
    const float* __restrict__ maxd_p,
    float* __restrict__ out)
{
    __shared__ float sP[S_][12];   // P = (K @ ext)[:3,:4] per view

    int t = threadIdx.x;
    if (t < S_ * 12) {
        int s = t / 12, e = t % 12, r = e >> 2, c = e & 3;
        float acc = 0.f;
#pragma unroll
        for (int j = 0; j < 4; ++j)
            acc += Ks[s * 16 + r * 4 + j] * ext[s * 16 + j * 4 + c];
        sP[s][e] = acc;
    }
    __syncthreads();

    int l4 = t & 3;
    int d  = t >> 2;                 // 0..63: wave wv covers d = wv*16 .. wv*16+15
    int n0 = blockIdx.x * 4;         // block's pixel-quad base
    int n  = n0 + l4;
    int w = n % W_, h = n / W_;

    // per-lane depth plane (same formula as reference / previous rounds)
    float mind = mind_p[0], maxd = maxd_p[0];
    float depth = expf(logf(mind) + logf(maxd / mind) * ((float)d / (float)(D_ - 1)));

    // ray = invK[:3,:3] @ (w+0.5, h+0.5, 1)
    float pxc = w + 0.5f, pyc = h + 0.5f;
    float rx = invK[0] * pxc + invK[1] * pyc + invK[2];
    float ry = invK[4] * pxc + invK[5] * pyc + invK[6];
    float rz = invK[8] * pxc + invK[9] * pyc + invK[10];

    float wx = rx * depth, wy = ry * depth, wz = rz * depth;

    // cur-feature quarter l4 for the quad's 4 pixels (block-shared -> L1/TA merge)
    float4 cfq[4];
#pragma unroll
    for (int j = 0; j < 4; ++j)
        cfq[j] = *(const float4*)(cur_t + (n0 + j) * C_ + l4 * 4);

    float pc[4] = {0.f, 0.f, 0.f, 0.f};  // partial (quarter) dot per quad output
    float mcnt = 0.f;                    // own-output mask count

#pragma unroll
    for (int s = 0; s < S_; ++s) {
        const float* p = sP[s];
        float cx = p[0] * wx + p[1] * wy + p[2]  * wz + p[3];
        float cy = p[4] * wx + p[5] * wy + p[6]  * wz + p[7];
        float cz = p[8] * wx + p[9] * wy + p[10] * wz + p[11];

        float iz = 1.f / (cz + EPS_PROJ);
        float x = cx * iz - 0.5f;
        float y = cy * iz - 0.5f;

        mcnt += (cz > 0.f) ? 1.f : 0.f;
        if (cz <= 0.f) { x = -1e8f; y = -1e8f; }   // all corner weights -> 0

        const float* sf = src_t + s * (C_ * N_) + l4 * 4;  // quarter-offset base

        // broadcast quad pixels' coords (all 4 lanes share this quad's depth)
        float xj[4], yj[4];
#pragma unroll
        for (int j = 0; j < 4; ++j) {
            xj[j] = __shfl(x, j, 4);
            yj[j] = __shfl(y, j, 4);
        }

        // --- phase A: all 16 corner offsets + weights ---
        int   off[16];
        float wgt[16];
#pragma unroll
        for (int j = 0; j < 4; ++j) {
            float x0f = floorf(xj[j]), y0f = floorf(yj[j]);
            float fx1 = xj[j] - x0f,  fy1 = yj[j] - y0f;
            float fx0 = 1.f - fx1, fy0 = 1.f - fy1;
            float x1f = x0f + 1.f, y1f = y0f + 1.f;

            float vx0 = (x0f >= 0.f && x0f <= (float)(W_ - 1)) ? fx0 : 0.f;
            float vx1 = (x1f >= 0.f && x1f <= (float)(W_ - 1)) ? fx1 : 0.f;
            float vy0 = (y0f >= 0.f && y0f <= (float)(H_ - 1)) ? fy0 : 0.f;
            float vy1 = (y1f >= 0.f && y1f <= (float)(H_ - 1)) ? fy1 : 0.f;

            int ix0 = (int)fminf(fmaxf(x0f, 0.f), (float)(W_ - 1));
            int ix1 = (int)fminf(fmaxf(x1f, 0.f), (float)(W_ - 1));
            int iy0 = (int)fminf(fmaxf(y0f, 0.f), (float)(H_ - 1));
            int iy1 = (int)fminf(fmaxf(y1f, 0.f), (float)(H_ - 1));

            int r0 = iy0 * W_, r1 = iy1 * W_;
            off[j * 4 + 0] = (r0 + ix0) * C_;
            off[j * 4 + 1] = (r0 + ix1) * C_;
            off[j * 4 + 2] = (r1 + ix0) * C_;
            off[j * 4 + 3] = (r1 + ix1) * C_;
            wgt[j * 4 + 0] = vx0 * vy0;
            wgt[j * 4 + 1] = vx1 * vy0;
            wgt[j * 4 + 2] = vx0 * vy1;
            wgt[j * 4 + 3] = vx1 * vy1;
        }

        // --- phase B: issue all 16 gathers as a batch ---
        float4 g[16];
#pragma unroll
        for (int k = 0; k < 16; ++k)
            g[k] = *(const float4*)(sf + off[k]);

        // --- phase C: dots + weighted accumulate ---
#pragma unroll
        for (int j = 0; j < 4; ++j) {
            float4 cq = cfq[j];
#pragma unroll
            for (int c = 0; c < 4; ++c) {
                float4 gv = g[j * 4 + c];
                float dt = gv.x * cq.x + gv.y * cq.y + gv.z * cq.z + gv.w * cq.w;
                pc[j] += wgt[j * 4 + c] * dt;
            }
        }
    }

    // quad reduction: full sum for each quad output
#pragma unroll
    for (int j = 0; j < 4; ++j) {
        pc[j] += __shfl_xor(pc[j], 1, 4);
        pc[j] += __shfl_xor(pc[j], 2, 4);
    }
    float total = (l4 == 0) ? pc[0] : (l4 == 1) ? pc[1] : (l4 == 2) ? pc[2] : pc[3];
    out[d * N_ + n0 + l4] = total / (mcnt + EPS_DIV);
}

// ---- fallback scalar kernel (no workspace): src (S,C,N), cur (C,N) ----
__global__ __launch_bounds__(256) void cost_volume_scalar(
    const float* __restrict__ src, const float* __restrict__ cur,
    const float* __restrict__ Ks, const float* __restrict__ ext,
    const float* __restrict__ invK,
    const float* __restrict__ mind_p, const float* __restrict__ maxd_p,
    float* __restrict__ out)
{
    __shared__ float sP[S_][12];
    __shared__ float sdepth;
    int t = threadIdx.x;
    if (t < S_ * 12) {
        int s = t / 12, e = t % 12, r = e >> 2, c = e & 3;
        float acc = 0.f;
#pragma unroll
        for (int j = 0; j < 4; ++j)
            acc += Ks[s * 16 + r * 4 + j] * ext[s * 16 + j * 4 + c];
        sP[s][e] = acc;
    }
    if (t == 0) {
        int d = (blockIdx.x * 256) / N_;
        float mind = mind_p[0], maxd = maxd_p[0];
        sdepth = expf(logf(mind) + logf(maxd / mind) * ((float)d / (float)(D_ - 1)));
    }
    __syncthreads();

    int tid = blockIdx.x * 256 + t;
    int n = tid % N_;
    int w = n % W_, h = n / W_;
    float pxc = w + 0.5f, pyc = h + 0.5f;
    float rx = invK[0] * pxc + invK[1] * pyc + invK[2];
    float ry = invK[4] * pxc + invK[5] * pyc + invK[6];
    float rz = invK[8] * pxc + invK[9] * pyc + invK[10];
    float depth = sdepth;
    float wx = rx * depth, wy = ry * depth, wz = rz * depth;

    float cf[16];
#pragma unroll
    for (int c = 0; c < 16; ++c) cf[c] = cur[c * N_ + n];

    float cost = 0.f, mcnt = 0.f;
#pragma unroll
    for (int s = 0; s < S_; ++s) {
        const float* p = sP[s];
        float cx = p[0] * wx + p[1] * wy + p[2]  * wz + p[3];
        float cy = p[4] * wx + p[5] * wy + p[6]  * wz + p[7];
        float cz = p[8] * wx + p[9] * wy + p[10] * wz + p[11];
        float iz = 1.f / (cz + EPS_PROJ);
        float x = cx * iz - 0.5f;
        float y = cy * iz - 0.5f;
        float x0f = floorf(x), y0f = floorf(y);
        float fx1 = x - x0f, fy1 = y - y0f;
        float fx0 = 1.f - fx1, fy0 = 1.f - fy1;
        const float* sf = src + (size_t)s * (C_ * N_);
        float dsum = 0.f;
        float ys[2] = {y0f, y0f + 1.f}, wys[2] = {fy0, fy1};
        float xs[2] = {x0f, x0f + 1.f}, wxs[2] = {fx0, fx1};
#pragma unroll
        for (int ci = 0; ci < 2; ++ci) {
            float yf = ys[ci];
            if (!(yf >= 0.f && yf <= (float)(H_ - 1))) continue;
            int rowbase = (int)yf * W_;
#pragma unroll
            for (int cj = 0; cj < 2; ++cj) {
                float xf = xs[cj];
                if (xf >= 0.f && xf <= (float)(W_ - 1)) {
                    int idx = rowbase + (int)xf;
                    float dotp = 0.f;
#pragma unroll
                    for (int c = 0; c < 16; ++c) dotp += sf[c * N_ + idx] * cf[c];
                    dsum += wxs[cj] * wys[ci] * dotp;
                }
            }
        }
        float m = (cz > 0.f) ? 1.f : 0.f;
        cost += m * dsum;
        mcnt += m;
    }
    out[tid] = cost / (mcnt + EPS_DIV);
}

extern "C" void kernel_launch(void* const* d_in, const int* in_sizes, int n_in,
                              void* d_out, int out_size, void* d_ws, size_t ws_size,
                              hipStream_t stream) {
    const float* cur  = (const float*)d_in[0];  // (1,C,H,W)
    const float* src  = (const float*)d_in[1];  // (1,S,C,H,W)
    const float* ext  = (const float*)d_in[2];  // (1,S,4,4)
    // d_in[3] = src_poses (unused by reference)
    const float* Ks   = (const float*)d_in[4];  // (1,S,4,4)
    const float* invK = (const float*)d_in[5];  // (1,4,4)
    const float* mind = (const float*)d_in[6];
    const float* maxd = (const float*)d_in[7];
    float* out = (float*)d_out;                 // (1,D,H,W)

    const size_t need = (size_t)(S_ * N_ * C_ + N_ * C_) * sizeof(float); // ~3.15 MB
    if (ws_size >= need) {
        float* src_t = (float*)d_ws;
        float* cur_t = src_t + (size_t)S_ * N_ * C_;
        const int tot = (S_ + 1) * C_ * N_;
        transpose_all<<<(tot + 255) / 256, 256, 0, stream>>>(src, cur, src_t, cur_t);
        cost_volume_quad_d<<<N_ / 4, 256, 0, stream>>>(   // 1536 blocks: one pixel-quad x 64 depths
            src_t, cur_t, Ks, ext, invK, mind, maxd, out);
    } else {
        cost_volume_scalar<<<D_ * N_ / 256, 256, 0, stream>>>(
            src, cur, Ks, ext, invK, mind, maxd, out);
    }
}